// Round 2
// baseline (63.802 us; speedup 1.0000x reference)
//
#include <hip/hip_runtime.h>
#include <hip/hip_bf16.h>

#define NB 4
#define NC 32
#define H0 64
#define W0 128
#define D0 12
#define H1 128
#define W1 256
#define NK 5     // 2*maxdisp1-1
#define IMH 512
#define IMW 1024

// ---------------------------------------------------------------------------
// clamp-to-edge bilinear sample (matches jax.image.resize upsample semantics:
// triangle kernel + border renormalization == clamped bilinear)
// ---------------------------------------------------------------------------
__device__ __forceinline__ float bilin(const float* __restrict__ img, int H, int W,
                                       float sy, float sx) {
    float y0f = floorf(sy), x0f = floorf(sx);
    float fy = sy - y0f, fx = sx - x0f;
    int y0 = (int)y0f, x0 = (int)x0f;
    int y0c = min(max(y0, 0), H - 1);
    int y1c = min(max(y0 + 1, 0), H - 1);
    int x0c = min(max(x0, 0), W - 1);
    int x1c = min(max(x0 + 1, 0), W - 1);
    float v00 = img[y0c * W + x0c];
    float v01 = img[y0c * W + x1c];
    float v10 = img[y1c * W + x0c];
    float v11 = img[y1c * W + x1c];
    float a = v00 * (1.f - fx) + v01 * fx;
    float b = v10 * (1.f - fx) + v11 * fx;
    return a * (1.f - fy) + b * fy;
}

// ---------------------------------------------------------------------------
// K1: scale-0 cost volume + softmax regression -> pred_low0 [B,H0,W0] (x8)
// one block per (b,h) row, 128 threads (w)
// ---------------------------------------------------------------------------
__global__ void k_cost0(const float* __restrict__ fl, const float* __restrict__ fr,
                        float* __restrict__ pred_low0) {
    const int bh = blockIdx.x;
    const int b = bh / H0, h = bh % H0;
    const int w = threadIdx.x;
    __shared__ float srow[W0];

    float cost[D0];
#pragma unroll
    for (int d = 0; d < D0; ++d) cost[d] = 0.f;

    for (int c = 0; c < NC; ++c) {
        const size_t idx = ((size_t)(b * NC + c) * H0 + h) * W0 + w;
        float flv = fl[idx];
        __syncthreads();
        srow[w] = fr[idx];
        __syncthreads();
#pragma unroll
        for (int d = 0; d < D0; ++d) {
            float rv = (w >= d) ? srow[w - d] : 0.f;
            cost[d] += fabsf(flv - rv);
        }
    }
    // softmax(-cost) weighted by d
    float m = cost[0];
#pragma unroll
    for (int d = 1; d < D0; ++d) m = fminf(m, cost[d]);
    float s = 0.f, sd = 0.f;
#pragma unroll
    for (int d = 0; d < D0; ++d) {
        float e = expf(m - cost[d]);
        s += e;
        sd += (float)d * e;
    }
    pred_low0[(size_t)bh * W0 + w] = 8.f * (sd / s);
}

// ---------------------------------------------------------------------------
// K2: wflow = 0.25 * antialiased-downsample_x4( upsample_x8(pred_low0) )
// one thread per wflow element [B,H1,W1]
// ---------------------------------------------------------------------------
__global__ void k_wflow(const float* __restrict__ pl0, float* __restrict__ wflow) {
    int t = blockIdx.x * blockDim.x + threadIdx.x;
    if (t >= NB * H1 * W1) return;
    int ox = t % W1;
    int tmp = t / W1;
    int oy = tmp % H1;
    int b = tmp / H1;
    const float* img = pl0 + (size_t)b * H0 * W0;

    const float wt[8] = {0.125f, 0.375f, 0.625f, 0.875f, 0.875f, 0.625f, 0.375f, 0.125f};
    float acc = 0.f, wsum = 0.f;
#pragma unroll
    for (int ty = 0; ty < 8; ++ty) {
        int y = 4 * oy - 2 + ty;
        if (y < 0 || y >= IMH) continue;
        float wy = wt[ty];
        float sy = (y + 0.5f) * 0.125f - 0.5f;
#pragma unroll
        for (int tx = 0; tx < 8; ++tx) {
            int x = 4 * ox - 2 + tx;
            if (x < 0 || x >= IMW) continue;
            float wx = wt[tx];
            float sx = (x + 0.5f) * 0.125f - 0.5f;
            acc += wy * wx * bilin(img, H0, W0, sy, sx);
            wsum += wy * wx;
        }
    }
    wflow[t] = 0.25f * (acc / wsum);
}

// ---------------------------------------------------------------------------
// K3: scale-1 residual cost volume (warp around wflow) + regression -> pred_low1 (x4)
// one block per (b,h) row, 256 threads (w)
// ---------------------------------------------------------------------------
__global__ void k_cost1(const float* __restrict__ fl, const float* __restrict__ fr,
                        const float* __restrict__ wflow, float* __restrict__ pred_low1) {
    const int bh = blockIdx.x;
    const int b = bh / H1, h = bh % H1;
    const int w = threadIdx.x;
    __shared__ float srow[W1];

    float disp = wflow[(size_t)bh * W1 + w];
    int xi0[NK];
    float frw[NK];
#pragma unroll
    for (int k = 0; k < NK; ++k) {
        float bd = disp - (float)(k - 2);       // shift = k-2 in [-2,2]
        float xs = (float)w - bd;               // sample position
        float x0f = floorf(xs);
        frw[k] = xs - x0f;
        xi0[k] = (int)x0f;
    }

    float cost[NK];
#pragma unroll
    for (int k = 0; k < NK; ++k) cost[k] = 0.f;

    for (int c = 0; c < NC; ++c) {
        const size_t idx = ((size_t)(b * NC + c) * H1 + h) * W1 + w;
        float flv = fl[idx];
        __syncthreads();
        srow[w] = fr[idx];
        __syncthreads();
#pragma unroll
        for (int k = 0; k < NK; ++k) {
            int x0 = xi0[k], x1 = x0 + 1;
            float g0 = (x0 >= 0 && x0 < W1) ? srow[x0] : 0.f;
            float g1 = (x1 >= 0 && x1 < W1) ? srow[x1] : 0.f;
            float v = g0 * (1.f - frw[k]) + g1 * frw[k];
            cost[k] += fabsf(flv - v);
        }
    }

    float m = cost[0];
#pragma unroll
    for (int k = 1; k < NK; ++k) m = fminf(m, cost[k]);
    float s = 0.f, sd = 0.f;
#pragma unroll
    for (int k = 0; k < NK; ++k) {
        float e = expf(m - cost[k]);
        s += e;
        sd += (float)(k - 2) * e;
    }
    pred_low1[(size_t)bh * W1 + w] = 4.f * (sd / s);
}

// ---------------------------------------------------------------------------
// K4: final — pred0 = up8(pred_low0); pred1 = up4(pred_low1) + pred0; write fp32
// one thread per full-res pixel
// ---------------------------------------------------------------------------
__global__ void k_final(const float* __restrict__ pl0, const float* __restrict__ pl1,
                        float* __restrict__ out) {
    int t = blockIdx.x * blockDim.x + threadIdx.x;
    if (t >= NB * IMH * IMW) return;
    int x = t % IMW;
    int tmp = t / IMW;
    int y = tmp % IMH;
    int b = tmp / IMH;

    float sy0 = (y + 0.5f) * 0.125f - 0.5f;
    float sx0 = (x + 0.5f) * 0.125f - 0.5f;
    float p0 = bilin(pl0 + (size_t)b * H0 * W0, H0, W0, sy0, sx0);

    float sy1 = (y + 0.5f) * 0.25f - 0.5f;
    float sx1 = (x + 0.5f) * 0.25f - 0.5f;
    float p1 = bilin(pl1 + (size_t)b * H1 * W1, H1, W1, sy1, sx1) + p0;

    out[t] = p0;
    out[(size_t)NB * IMH * IMW + t] = p1;
}

// ---------------------------------------------------------------------------
extern "C" void kernel_launch(void* const* d_in, const int* in_sizes, int n_in,
                              void* d_out, int out_size, void* d_ws, size_t ws_size,
                              hipStream_t stream) {
    const float* fl0 = (const float*)d_in[0];
    const float* fr0 = (const float*)d_in[1];
    const float* fl1 = (const float*)d_in[2];
    const float* fr1 = (const float*)d_in[3];
    float* out = (float*)d_out;

    float* ws = (float*)d_ws;
    float* pred_low0 = ws;                         // NB*H0*W0   = 32768 floats
    float* wflow     = ws + 32768;                 // NB*H1*W1   = 131072 floats
    float* pred_low1 = ws + 32768 + 131072;        // NB*H1*W1   = 131072 floats

    k_cost0<<<NB * H0, W0, 0, stream>>>(fl0, fr0, pred_low0);

    int n_wf = NB * H1 * W1;
    k_wflow<<<(n_wf + 255) / 256, 256, 0, stream>>>(pred_low0, wflow);

    k_cost1<<<NB * H1, W1, 0, stream>>>(fl1, fr1, wflow, pred_low1);

    int n_px = NB * IMH * IMW;
    k_final<<<(n_px + 255) / 256, 256, 0, stream>>>(pred_low0, pred_low1, out);
}

// Round 3
// 28.453 us; speedup vs baseline: 2.2424x; 2.2424x over previous
//
#include <hip/hip_runtime.h>

#define NB 4
#define NC 32
#define H0 64
#define W0 128
#define D0 12
#define H1 128
#define W1 256
#define NK 5     // 2*maxdisp1-1
#define IMH 512
#define IMW 1024

// ---------------------------------------------------------------------------
// clamp-to-edge bilinear (jax.image.resize upsample == clamped bilinear)
// ---------------------------------------------------------------------------
__device__ __forceinline__ float bilin(const float* __restrict__ img, int H, int W,
                                       float sy, float sx) {
    float y0f = floorf(sy), x0f = floorf(sx);
    float fy = sy - y0f, fx = sx - x0f;
    int y0 = (int)y0f, x0 = (int)x0f;
    int y0c = min(max(y0, 0), H - 1);
    int y1c = min(max(y0 + 1, 0), H - 1);
    int x0c = min(max(x0, 0), W - 1);
    int x1c = min(max(x0 + 1, 0), W - 1);
    float v00 = img[y0c * W + x0c];
    float v01 = img[y0c * W + x1c];
    float v10 = img[y1c * W + x0c];
    float v11 = img[y1c * W + x1c];
    float a = v00 * (1.f - fx) + v01 * fx;
    float b = v10 * (1.f - fx) + v11 * fx;
    return a * (1.f - fy) + b * fy;
}

// ---------------------------------------------------------------------------
// K1: scale-0 cost volume + regression. grid = NB*H0, block = 512
// (4 channel-groups x 128 w). Single-sync LDS staging of the fr row.
// ---------------------------------------------------------------------------
__global__ __launch_bounds__(512) void k_cost0(const float* __restrict__ fl,
                                               const float* __restrict__ fr,
                                               float* __restrict__ pl0) {
    const int bh = blockIdx.x;              // b*H0 + h
    const int b = bh >> 6, h = bh & (H0 - 1);
    const int tid = threadIdx.x;
    __shared__ float frs[NC][W0];           // 16 KB
    __shared__ float part[4][D0][W0];       // 24 KB

    const size_t rowbase = ((size_t)b * NC * H0 + h) * W0;   // + c*H0*W0 + w

    // stage all 32 channels of the fr row, float4, one sync
#pragma unroll
    for (int i = 0; i < 2; ++i) {
        int f4 = i * 512 + tid;             // 1024 float4s total
        int c = f4 >> 5, w4 = f4 & 31;      // 32 float4 per row
        ((float4*)frs)[f4] =
            *(const float4*)(fr + rowbase + (size_t)c * (H0 * W0) + w4 * 4);
    }
    __syncthreads();

    const int g = tid >> 7, w = tid & (W0 - 1);
    float cost[D0];
#pragma unroll
    for (int d = 0; d < D0; ++d) cost[d] = 0.f;
#pragma unroll
    for (int j = 0; j < 8; ++j) {
        int c = g * 8 + j;
        float flv = fl[rowbase + (size_t)c * (H0 * W0) + w];
#pragma unroll
        for (int d = 0; d < D0; ++d) {
            float rv = (w >= d) ? frs[c][w - d] : 0.f;
            cost[d] += fabsf(flv - rv);
        }
    }
#pragma unroll
    for (int d = 0; d < D0; ++d) part[g][d][w] = cost[d];
    __syncthreads();

    if (tid < W0) {
        float tc[D0];
#pragma unroll
        for (int d = 0; d < D0; ++d)
            tc[d] = part[0][d][tid] + part[1][d][tid] + part[2][d][tid] + part[3][d][tid];
        float m = tc[0];
#pragma unroll
        for (int d = 1; d < D0; ++d) m = fminf(m, tc[d]);
        float s = 0.f, sd = 0.f;
#pragma unroll
        for (int d = 0; d < D0; ++d) {
            float e = expf(m - tc[d]);
            s += e;
            sd += (float)d * e;
        }
        pl0[(size_t)bh * W0 + tid] = 8.f * (sd / s);
    }
}

// ---------------------------------------------------------------------------
// K2: fused wflow (exact 3x3 composite of up8 then antialiased down4, scaled
// by 0.25) + scale-1 residual cost volume + regression.
// grid = NB*H1, block = 512 (2 channel-halves x 256 w).
// ---------------------------------------------------------------------------
__global__ __launch_bounds__(512) void k_cost1(const float* __restrict__ fl,
                                               const float* __restrict__ fr,
                                               const float* __restrict__ pl0,
                                               float* __restrict__ pl1) {
    const int bh = blockIdx.x;              // b*H1 + oy
    const int b = bh >> 7, oy = bh & (H1 - 1);
    const int tid = threadIdx.x;
    __shared__ float frs[NC][W1];           // 32 KB
    __shared__ float part[2][NK][W1];       // 10 KB
    __shared__ float ytmp[W0];
    __shared__ float wfl[W1];

    const size_t rowbase = ((size_t)b * NC * H1 + oy) * W1;  // + c*H1*W1 + w

    // ---- phase A: y-composite filter of pl0 into ytmp (tid < 128) ----
    if (tid < W0) {
        const float* p0b = pl0 + (size_t)b * H0 * W0;
        int m = oy >> 1;
        int r0, r1, r2;
        float wy0, wy1, wy2;
        if (oy == 0) {
            r0 = 0; r1 = 0; r2 = 1;
            wy0 = 0.f; wy1 = 27.625f / 28.f; wy2 = 0.375f / 28.f;
        } else if (oy == H1 - 1) {
            r0 = H0 - 2; r1 = H0 - 1; r2 = H0 - 1;
            wy0 = 0.375f / 28.f; wy1 = 27.625f / 28.f; wy2 = 0.f;
        } else {
            r0 = max(m - 1, 0); r1 = m; r2 = min(m + 1, H0 - 1);
            if (oy & 1) { wy0 = 0.375f / 32.f; wy1 = 23.25f / 32.f; wy2 = 8.375f / 32.f; }
            else        { wy0 = 8.375f / 32.f; wy1 = 23.25f / 32.f; wy2 = 0.375f / 32.f; }
        }
        ytmp[tid] = wy0 * p0b[r0 * W0 + tid] + wy1 * p0b[r1 * W0 + tid]
                  + wy2 * p0b[r2 * W0 + tid];
    }

    // ---- stage fr row (all 32 channels), float4 ----
#pragma unroll
    for (int i = 0; i < 4; ++i) {
        int f4 = i * 512 + tid;             // 2048 float4s
        int c = f4 >> 6, w4 = f4 & 63;      // 64 float4 per row
        ((float4*)frs)[f4] =
            *(const float4*)(fr + rowbase + (size_t)c * (H1 * W1) + w4 * 4);
    }
    __syncthreads();

    // ---- phase B: x-composite into wfl (tid < 256) ----
    if (tid < W1) {
        int ox = tid, n = ox >> 1;
        int c0, c1, c2;
        float wx0, wx1, wx2;
        if (ox == 0) {
            c0 = 0; c1 = 0; c2 = 1;
            wx0 = 0.f; wx1 = 27.625f / 28.f; wx2 = 0.375f / 28.f;
        } else if (ox == W1 - 1) {
            c0 = W0 - 2; c1 = W0 - 1; c2 = W0 - 1;
            wx0 = 0.375f / 28.f; wx1 = 27.625f / 28.f; wx2 = 0.f;
        } else {
            c0 = max(n - 1, 0); c1 = n; c2 = min(n + 1, W0 - 1);
            if (ox & 1) { wx0 = 0.375f / 32.f; wx1 = 23.25f / 32.f; wx2 = 8.375f / 32.f; }
            else        { wx0 = 8.375f / 32.f; wx1 = 23.25f / 32.f; wx2 = 0.375f / 32.f; }
        }
        wfl[ox] = 0.25f * (wx0 * ytmp[c0] + wx1 * ytmp[c1] + wx2 * ytmp[c2]);
    }
    __syncthreads();

    // ---- phase C: residual cost over 16 channels per half ----
    const int half = tid >> 8, w = tid & (W1 - 1);
    float disp = wfl[w];
    int xi0[NK];
    float frw[NK];
#pragma unroll
    for (int k = 0; k < NK; ++k) {
        float xs = (float)w - disp + (float)(k - 2);
        float x0f = floorf(xs);
        frw[k] = xs - x0f;
        xi0[k] = (int)x0f;
    }
    float cost[NK];
#pragma unroll
    for (int k = 0; k < NK; ++k) cost[k] = 0.f;
#pragma unroll
    for (int j = 0; j < 16; ++j) {
        int c = half * 16 + j;
        float flv = fl[rowbase + (size_t)c * (H1 * W1) + w];
#pragma unroll
        for (int k = 0; k < NK; ++k) {
            int x0 = xi0[k], x1 = x0 + 1;
            float g0 = (x0 >= 0 && x0 < W1) ? frs[c][x0] : 0.f;
            float g1 = (x1 >= 0 && x1 < W1) ? frs[c][x1] : 0.f;
            cost[k] += fabsf(flv - (g0 * (1.f - frw[k]) + g1 * frw[k]));
        }
    }
#pragma unroll
    for (int k = 0; k < NK; ++k) part[half][k][w] = cost[k];
    __syncthreads();

    if (tid < W1) {
        float tc[NK];
#pragma unroll
        for (int k = 0; k < NK; ++k) tc[k] = part[0][k][tid] + part[1][k][tid];
        float m = tc[0];
#pragma unroll
        for (int k = 1; k < NK; ++k) m = fminf(m, tc[k]);
        float s = 0.f, sd = 0.f;
#pragma unroll
        for (int k = 0; k < NK; ++k) {
            float e = expf(m - tc[k]);
            s += e;
            sd += (float)(k - 2) * e;
        }
        pl1[(size_t)bh * W1 + tid] = 4.f * (sd / s);
    }
}

// ---------------------------------------------------------------------------
// K3: final — pred0 = up8(pl0); pred1 = up4(pl1) + pred0. 4 px/thread,
// float4 stores.
// ---------------------------------------------------------------------------
__global__ void k_final(const float* __restrict__ pl0, const float* __restrict__ pl1,
                        float* __restrict__ out) {
    const int NPX = NB * IMH * IMW;
    int t = blockIdx.x * blockDim.x + threadIdx.x;
    if (t >= NPX / 4) return;
    int xq = t & (IMW / 4 - 1);
    int tmp = t >> 8;                        // / (IMW/4)
    int y = tmp & (IMH - 1);
    int b = tmp >> 9;                        // / IMH

    const float* p0b = pl0 + (size_t)b * H0 * W0;
    const float* p1b = pl1 + (size_t)b * H1 * W1;
    float sy0 = (y + 0.5f) * 0.125f - 0.5f;
    float sy1 = (y + 0.5f) * 0.25f - 0.5f;

    float v0[4], v1[4];
#pragma unroll
    for (int i = 0; i < 4; ++i) {
        int x = xq * 4 + i;
        float sx0 = (x + 0.5f) * 0.125f - 0.5f;
        float sx1 = (x + 0.5f) * 0.25f - 0.5f;
        float p0 = bilin(p0b, H0, W0, sy0, sx0);
        v0[i] = p0;
        v1[i] = bilin(p1b, H1, W1, sy1, sx1) + p0;
    }
    ((float4*)out)[t] = make_float4(v0[0], v0[1], v0[2], v0[3]);
    ((float4*)(out + NPX))[t] = make_float4(v1[0], v1[1], v1[2], v1[3]);
}

// ---------------------------------------------------------------------------
extern "C" void kernel_launch(void* const* d_in, const int* in_sizes, int n_in,
                              void* d_out, int out_size, void* d_ws, size_t ws_size,
                              hipStream_t stream) {
    const float* fl0 = (const float*)d_in[0];
    const float* fr0 = (const float*)d_in[1];
    const float* fl1 = (const float*)d_in[2];
    const float* fr1 = (const float*)d_in[3];
    float* out = (float*)d_out;

    float* ws = (float*)d_ws;
    float* pred_low0 = ws;                   // NB*H0*W0 = 32768 floats
    float* pred_low1 = ws + 32768;           // NB*H1*W1 = 131072 floats

    k_cost0<<<NB * H0, 512, 0, stream>>>(fl0, fr0, pred_low0);
    k_cost1<<<NB * H1, 512, 0, stream>>>(fl1, fr1, pred_low0, pred_low1);

    int n4 = NB * IMH * IMW / 4;             // 524288
    k_final<<<(n4 + 255) / 256, 256, 0, stream>>>(pred_low0, pred_low1, out);
}

// Round 5
// 26.618 us; speedup vs baseline: 2.3969x; 1.0689x over previous
//
#include <hip/hip_runtime.h>

#define NB 4
#define NC 32
#define H0 64
#define W0 128
#define D0 12
#define H1 128
#define W1 256
#define NK 5
#define IMH 512
#define IMW 1024

#define FR0_STRIDE 84    // 16 guard + 64 data + 4 pad (bank-spread, 16B-aligned)
#define FR0_GUARD  16
#define FR1_STRIDE 288   // 28 left guard + 256 data + 4 right guard
#define FR1_GUARD  28

typedef __attribute__((address_space(3))) uint32_t as3_u32;
typedef const __attribute__((address_space(1))) uint32_t as1_u32;

__device__ __forceinline__ float bilin(const float* __restrict__ img, int H, int W,
                                       float sy, float sx) {
    float y0f = floorf(sy), x0f = floorf(sx);
    float fy = sy - y0f, fx = sx - x0f;
    int y0 = (int)y0f, x0 = (int)x0f;
    int y0c = min(max(y0, 0), H - 1);
    int y1c = min(max(y0 + 1, 0), H - 1);
    int x0c = min(max(x0, 0), W - 1);
    int x1c = min(max(x0 + 1, 0), W - 1);
    float v00 = img[y0c * W + x0c];
    float v01 = img[y0c * W + x1c];
    float v10 = img[y1c * W + x0c];
    float v11 = img[y1c * W + x1c];
    float a = v00 * (1.f - fx) + v01 * fx;
    float b = v10 * (1.f - fx) + v11 * fx;
    return a * (1.f - fy) + b * fy;
}

// ---------------------------------------------------------------------------
// K1: scale-0 cost volume + regression. 512 blocks (half-rows) x 512 threads.
// Layout: wloc = tid>>3 (64 w per half-row), g = tid&7, channels c = g+8j.
// ---------------------------------------------------------------------------
__global__ __launch_bounds__(512) void k_cost0(const float* __restrict__ fl,
                                               const float* __restrict__ fr,
                                               float* __restrict__ pl0) {
    const int blk = blockIdx.x;          // 0..511
    const int row = blk >> 1;            // b*H0 + h
    const int half = blk & 1;
    const int w0 = half * 64;
    const int b = row >> 6, h = row & (H0 - 1);
    const int tid = threadIdx.x;
    __shared__ float frs[NC][FR0_STRIDE];

    const size_t rowbase = ((size_t)b * NC * H0 + h) * W0;   // + c*H0*W0 + w

    // stage fr cols [w0-16, w0+64): 20 float4 per channel, zeros where col<0
#pragma unroll
    for (int i = 0; i < 2; ++i) {
        int idx = i * 512 + tid;
        if (idx < NC * 20) {
            int c = idx / 20, q = idx - c * 20;
            int colg = w0 - 16 + q * 4;
            float4 v = make_float4(0.f, 0.f, 0.f, 0.f);
            if (colg >= 0)
                v = *(const float4*)(fr + rowbase + (size_t)c * (H0 * W0) + colg);
            *(float4*)&frs[c][q * 4] = v;
        }
    }
    __syncthreads();

    const int wloc = tid >> 3, g = tid & 7;
    float cost[D0];
#pragma unroll
    for (int d = 0; d < D0; ++d) cost[d] = 0.f;
#pragma unroll
    for (int j = 0; j < 4; ++j) {
        int c = g + 8 * j;
        float flv = fl[rowbase + (size_t)c * (H0 * W0) + w0 + wloc];
        const float* sr = &frs[c][FR0_GUARD + wloc];
#pragma unroll
        for (int d = 0; d < D0; ++d)
            cost[d] += fabsf(flv - sr[-d]);
    }
#pragma unroll
    for (int d = 0; d < D0; ++d) {
        cost[d] += __shfl_xor(cost[d], 1);
        cost[d] += __shfl_xor(cost[d], 2);
        cost[d] += __shfl_xor(cost[d], 4);
    }
    if (g == 0) {
        float m = cost[0];
#pragma unroll
        for (int d = 1; d < D0; ++d) m = fminf(m, cost[d]);
        float s = 0.f, sd = 0.f;
#pragma unroll
        for (int d = 0; d < D0; ++d) {
            float e = expf(m - cost[d]);
            s += e;
            sd += (float)d * e;
        }
        pl0[(size_t)row * W0 + w0 + wloc] = 8.f * (sd / s);
    }
}

// ---------------------------------------------------------------------------
// K2: fused wflow (exact 3x3 composite) + residual cost volume + regression.
// 512 blocks x 512 threads. fr1 row staged via global_load_lds (issued first,
// latency hidden under the wflow stencil phases).
// ---------------------------------------------------------------------------
__global__ __launch_bounds__(512) void k_cost1(const float* __restrict__ fl,
                                               const float* __restrict__ fr,
                                               const float* __restrict__ pl0,
                                               float* __restrict__ pl1) {
    const int blk = blockIdx.x;          // b*H1 + oy
    const int b = blk >> 7, oy = blk & (H1 - 1);
    const int tid = threadIdx.x;
    __shared__ float frs1p[NC][FR1_STRIDE];   // 36 KB
    __shared__ float ytmp[W0];
    __shared__ float wfl[W1];

    const size_t rowbase1 = ((size_t)b * NC * H1 + oy) * W1;   // + c*H1*W1

    // ---- issue async global->LDS staging first (32 rows x 64 float4) ----
    {
        const int wave = tid >> 6, lane = tid & 63;
#pragma unroll
        for (int j = 0; j < 4; ++j) {
            int c = wave * 4 + j;
            const float* src = fr + rowbase1 + (size_t)c * (H1 * W1) + lane * 4;
            as3_u32* dst = (as3_u32*)(&frs1p[c][FR1_GUARD]);
            __builtin_amdgcn_global_load_lds((as1_u32*)src, dst, 16, 0, 0);
        }
    }

    // ---- zero guard cols: 28 left + 4 right per row = 32 per row, 1024 total
#pragma unroll
    for (int i = 0; i < 2; ++i) {
        int idx = i * 512 + tid;
        int r = idx >> 5, q = idx & 31;
        int col = (q < FR1_GUARD) ? q : (FR1_GUARD + W1 + (q - FR1_GUARD));
        frs1p[r][col] = 0.f;
    }

    // ---- phase A: y-composite of pl0 into ytmp ----
    if (tid < W0) {
        const float* p0b = pl0 + (size_t)b * H0 * W0;
        int m = oy >> 1;
        int r0, r1, r2;
        float wy0, wy1, wy2;
        if (oy == 0) {
            r0 = 0; r1 = 0; r2 = 1;
            wy0 = 0.f; wy1 = 27.625f / 28.f; wy2 = 0.375f / 28.f;
        } else if (oy == H1 - 1) {
            r0 = H0 - 2; r1 = H0 - 1; r2 = H0 - 1;
            wy0 = 0.375f / 28.f; wy1 = 27.625f / 28.f; wy2 = 0.f;
        } else {
            r0 = max(m - 1, 0); r1 = m; r2 = min(m + 1, H0 - 1);
            if (oy & 1) { wy0 = 0.375f / 32.f; wy1 = 23.25f / 32.f; wy2 = 8.375f / 32.f; }
            else        { wy0 = 8.375f / 32.f; wy1 = 23.25f / 32.f; wy2 = 0.375f / 32.f; }
        }
        ytmp[tid] = wy0 * p0b[r0 * W0 + tid] + wy1 * p0b[r1 * W0 + tid]
                  + wy2 * p0b[r2 * W0 + tid];
    }
    __syncthreads();

    // ---- phase B: x-composite into wfl ----
    if (tid < W1) {
        int ox = tid, n = ox >> 1;
        int c0, c1, c2;
        float wx0, wx1, wx2;
        if (ox == 0) {
            c0 = 0; c1 = 0; c2 = 1;
            wx0 = 0.f; wx1 = 27.625f / 28.f; wx2 = 0.375f / 28.f;
        } else if (ox == W1 - 1) {
            c0 = W0 - 2; c1 = W0 - 1; c2 = W0 - 1;
            wx0 = 0.375f / 28.f; wx1 = 27.625f / 28.f; wx2 = 0.f;
        } else {
            c0 = max(n - 1, 0); c1 = n; c2 = min(n + 1, W0 - 1);
            if (ox & 1) { wx0 = 0.375f / 32.f; wx1 = 23.25f / 32.f; wx2 = 8.375f / 32.f; }
            else        { wx0 = 8.375f / 32.f; wx1 = 23.25f / 32.f; wx2 = 0.375f / 32.f; }
        }
        wfl[ox] = 0.25f * (wx0 * ytmp[c0] + wx1 * ytmp[c1] + wx2 * ytmp[c2]);
    }
    __syncthreads();   // wfl ready; barrier also drains global_load_lds (vmcnt 0)

    // ---- phase C: residual cost, shared-frac 6-tap window; c = 2j+h ----
    {
        const int w = tid >> 1, h = tid & 1;
        float disp = wfl[w];
        float xs = (float)w - disp;
        float xbf = floorf(xs);
        float f = xs - xbf;
        int xb = (int)xbf;                 // in [w-23, w]
        const float* sr = &frs1p[0][FR1_GUARD + xb - 2];

        float cost[NK];
#pragma unroll
        for (int k = 0; k < NK; ++k) cost[k] = 0.f;
#pragma unroll
        for (int j = 0; j < 16; ++j) {
            int c = 2 * j + h;
            float flv = fl[rowbase1 + (size_t)c * (H1 * W1) + w];
            const float* row = sr + c * FR1_STRIDE;
            float g0 = row[0], g1 = row[1], g2 = row[2];
            float g3 = row[3], g4 = row[4], g5 = row[5];
            cost[0] += fabsf(flv - (g0 + f * (g1 - g0)));
            cost[1] += fabsf(flv - (g1 + f * (g2 - g1)));
            cost[2] += fabsf(flv - (g2 + f * (g3 - g2)));
            cost[3] += fabsf(flv - (g3 + f * (g4 - g3)));
            cost[4] += fabsf(flv - (g4 + f * (g5 - g4)));
        }
#pragma unroll
        for (int k = 0; k < NK; ++k) cost[k] += __shfl_xor(cost[k], 1);
        if (h == 0) {
            float m = cost[0];
#pragma unroll
            for (int k = 1; k < NK; ++k) m = fminf(m, cost[k]);
            float s = 0.f, sd = 0.f;
#pragma unroll
            for (int k = 0; k < NK; ++k) {
                float e = expf(m - cost[k]);
                s += e;
                sd += (float)(k - 2) * e;
            }
            pl1[(size_t)blk * W1 + w] = 4.f * (sd / s);
        }
    }
}

// ---------------------------------------------------------------------------
// K3: final — pred0 = up8(pl0); pred1 = up4(pl1) + pred0. 4 px/thread, float4.
// ---------------------------------------------------------------------------
__global__ void k_final(const float* __restrict__ pl0, const float* __restrict__ pl1,
                        float* __restrict__ out) {
    const int NPX = NB * IMH * IMW;
    int t = blockIdx.x * blockDim.x + threadIdx.x;
    if (t >= NPX / 4) return;
    int xq = t & (IMW / 4 - 1);
    int tmp = t >> 8;
    int y = tmp & (IMH - 1);
    int b = tmp >> 9;

    const float* p0b = pl0 + (size_t)b * H0 * W0;
    const float* p1b = pl1 + (size_t)b * H1 * W1;
    float sy0 = (y + 0.5f) * 0.125f - 0.5f;
    float sy1 = (y + 0.5f) * 0.25f - 0.5f;

    float v0[4], v1[4];
#pragma unroll
    for (int i = 0; i < 4; ++i) {
        int x = xq * 4 + i;
        float sx0 = (x + 0.5f) * 0.125f - 0.5f;
        float sx1 = (x + 0.5f) * 0.25f - 0.5f;
        float p0 = bilin(p0b, H0, W0, sy0, sx0);
        v0[i] = p0;
        v1[i] = bilin(p1b, H1, W1, sy1, sx1) + p0;
    }
    ((float4*)out)[t] = make_float4(v0[0], v0[1], v0[2], v0[3]);
    ((float4*)(out + NPX))[t] = make_float4(v1[0], v1[1], v1[2], v1[3]);
}

// ---------------------------------------------------------------------------
extern "C" void kernel_launch(void* const* d_in, const int* in_sizes, int n_in,
                              void* d_out, int out_size, void* d_ws, size_t ws_size,
                              hipStream_t stream) {
    const float* fl0 = (const float*)d_in[0];
    const float* fr0 = (const float*)d_in[1];
    const float* fl1 = (const float*)d_in[2];
    const float* fr1 = (const float*)d_in[3];
    float* out = (float*)d_out;

    float* ws = (float*)d_ws;
    float* pl0 = ws;                 // 32768 floats
    float* pl1 = ws + 32768;         // 131072 floats

    k_cost0<<<NB * H0 * 2, 512, 0, stream>>>(fl0, fr0, pl0);
    k_cost1<<<NB * H1, 512, 0, stream>>>(fl1, fr1, pl0, pl1);

    int n4 = NB * IMH * IMW / 4;
    k_final<<<(n4 + 255) / 256, 256, 0, stream>>>(pl0, pl1, out);
}

// Round 6
// 26.273 us; speedup vs baseline: 2.4285x; 1.0132x over previous
//
#include <hip/hip_runtime.h>

#define NB 4
#define NC 32
#define H0 64
#define W0 128
#define D0 12
#define H1 128
#define W1 256
#define NK 5
#define IMH 512
#define IMW 1024

#define FR0_STRIDE 84    // 16 guard + 64 data + 4 pad (2-way-max bank spread)
#define FR0_GUARD  16
#define FR1_STRIDE 288   // 28 left guard + 256 data + 4 right guard
#define FR1_GUARD  28

typedef __attribute__((address_space(3))) uint32_t as3_u32;
typedef const __attribute__((address_space(1))) uint32_t as1_u32;

// ---------------------------------------------------------------------------
// K1: scale-0 cost volume + regression. 512 blocks (half-rows) x 512 threads.
// Layout: wloc = tid>>3 (64 w per half-row), g = tid&7, channels c = g+8j.
// fl values register-prefetched BEFORE the barrier (latency overlap).
// ---------------------------------------------------------------------------
__global__ __launch_bounds__(512) void k_cost0(const float* __restrict__ fl,
                                               const float* __restrict__ fr,
                                               float* __restrict__ pl0) {
    const int blk = blockIdx.x;          // 0..511
    const int row = blk >> 1;            // b*H0 + h
    const int half = blk & 1;
    const int w0 = half * 64;
    const int b = row >> 6, h = row & (H0 - 1);
    const int tid = threadIdx.x;
    __shared__ float frs[NC][FR0_STRIDE];

    const size_t rowbase = ((size_t)b * NC * H0 + h) * W0;   // + c*H0*W0 + w

    const int wloc = tid >> 3, g = tid & 7;

    // ---- prefetch fl into registers (independent of LDS; overlaps staging)
    float flv[4];
#pragma unroll
    for (int j = 0; j < 4; ++j)
        flv[j] = fl[rowbase + (size_t)(g + 8 * j) * (H0 * W0) + w0 + wloc];

    // ---- stage fr cols [w0-16, w0+64): 20 float4 per channel, zero where <0
#pragma unroll
    for (int i = 0; i < 2; ++i) {
        int idx = i * 512 + tid;
        if (idx < NC * 20) {
            int c = idx / 20, q = idx - c * 20;
            int colg = w0 - 16 + q * 4;
            float4 v = make_float4(0.f, 0.f, 0.f, 0.f);
            if (colg >= 0)
                v = *(const float4*)(fr + rowbase + (size_t)c * (H0 * W0) + colg);
            *(float4*)&frs[c][q * 4] = v;
        }
    }
    __syncthreads();

    float cost[D0];
#pragma unroll
    for (int d = 0; d < D0; ++d) cost[d] = 0.f;
#pragma unroll
    for (int j = 0; j < 4; ++j) {
        int c = g + 8 * j;
        const float* sr = &frs[c][FR0_GUARD + wloc];
#pragma unroll
        for (int d = 0; d < D0; ++d)
            cost[d] += fabsf(flv[j] - sr[-d]);
    }
#pragma unroll
    for (int d = 0; d < D0; ++d) {
        cost[d] += __shfl_xor(cost[d], 1);
        cost[d] += __shfl_xor(cost[d], 2);
        cost[d] += __shfl_xor(cost[d], 4);
    }
    if (g == 0) {
        float m = cost[0];
#pragma unroll
        for (int d = 1; d < D0; ++d) m = fminf(m, cost[d]);
        float s = 0.f, sd = 0.f;
#pragma unroll
        for (int d = 0; d < D0; ++d) {
            float e = expf(m - cost[d]);
            s += e;
            sd += (float)d * e;
        }
        pl0[(size_t)row * W0 + w0 + wloc] = 8.f * (sd / s);
    }
}

// ---------------------------------------------------------------------------
// K2: fused wflow (exact 3x3 composite) + residual cost volume + regression.
// 512 blocks x 512 threads. fr1 staged via global_load_lds issued first;
// fl1 register-prefetched; both latencies hidden under the stencil phases.
// ---------------------------------------------------------------------------
__global__ __launch_bounds__(512) void k_cost1(const float* __restrict__ fl,
                                               const float* __restrict__ fr,
                                               const float* __restrict__ pl0,
                                               float* __restrict__ pl1) {
    const int blk = blockIdx.x;          // b*H1 + oy
    const int b = blk >> 7, oy = blk & (H1 - 1);
    const int tid = threadIdx.x;
    __shared__ float frs1p[NC][FR1_STRIDE];   // 36 KB
    __shared__ float ytmp[W0];
    __shared__ float wfl[W1];

    const size_t rowbase1 = ((size_t)b * NC * H1 + oy) * W1;   // + c*H1*W1

    // ---- issue async global->LDS staging first (32 rows x 64 float4) ----
    {
        const int wave = tid >> 6, lane = tid & 63;
#pragma unroll
        for (int j = 0; j < 4; ++j) {
            int c = wave * 4 + j;
            const float* src = fr + rowbase1 + (size_t)c * (H1 * W1) + lane * 4;
            as3_u32* dst = (as3_u32*)(&frs1p[c][FR1_GUARD]);
            __builtin_amdgcn_global_load_lds((as1_u32*)src, dst, 16, 0, 0);
        }
    }

    // ---- register-prefetch fl1 (16 channels per thread; c = 2j+h) ----
    const int w = tid >> 1, hh = tid & 1;
    float flv[16];
#pragma unroll
    for (int j = 0; j < 16; ++j)
        flv[j] = fl[rowbase1 + (size_t)(2 * j + hh) * (H1 * W1) + w];

    // ---- zero guard cols: 28 left + 4 right per row = 32/row, 1024 total ----
#pragma unroll
    for (int i = 0; i < 2; ++i) {
        int idx = i * 512 + tid;
        int r = idx >> 5, q = idx & 31;
        int col = (q < FR1_GUARD) ? q : (FR1_GUARD + W1 + (q - FR1_GUARD));
        frs1p[r][col] = 0.f;
    }

    // ---- phase A: y-composite of pl0 into ytmp ----
    if (tid < W0) {
        const float* p0b = pl0 + (size_t)b * H0 * W0;
        int m = oy >> 1;
        int r0, r1, r2;
        float wy0, wy1, wy2;
        if (oy == 0) {
            r0 = 0; r1 = 0; r2 = 1;
            wy0 = 0.f; wy1 = 27.625f / 28.f; wy2 = 0.375f / 28.f;
        } else if (oy == H1 - 1) {
            r0 = H0 - 2; r1 = H0 - 1; r2 = H0 - 1;
            wy0 = 0.375f / 28.f; wy1 = 27.625f / 28.f; wy2 = 0.f;
        } else {
            r0 = max(m - 1, 0); r1 = m; r2 = min(m + 1, H0 - 1);
            if (oy & 1) { wy0 = 0.375f / 32.f; wy1 = 23.25f / 32.f; wy2 = 8.375f / 32.f; }
            else        { wy0 = 8.375f / 32.f; wy1 = 23.25f / 32.f; wy2 = 0.375f / 32.f; }
        }
        ytmp[tid] = wy0 * p0b[r0 * W0 + tid] + wy1 * p0b[r1 * W0 + tid]
                  + wy2 * p0b[r2 * W0 + tid];
    }
    __syncthreads();

    // ---- phase B: x-composite into wfl ----
    if (tid < W1) {
        int ox = tid, n = ox >> 1;
        int c0, c1, c2;
        float wx0, wx1, wx2;
        if (ox == 0) {
            c0 = 0; c1 = 0; c2 = 1;
            wx0 = 0.f; wx1 = 27.625f / 28.f; wx2 = 0.375f / 28.f;
        } else if (ox == W1 - 1) {
            c0 = W0 - 2; c1 = W0 - 1; c2 = W0 - 1;
            wx0 = 0.375f / 28.f; wx1 = 27.625f / 28.f; wx2 = 0.f;
        } else {
            c0 = max(n - 1, 0); c1 = n; c2 = min(n + 1, W0 - 1);
            if (ox & 1) { wx0 = 0.375f / 32.f; wx1 = 23.25f / 32.f; wx2 = 8.375f / 32.f; }
            else        { wx0 = 8.375f / 32.f; wx1 = 23.25f / 32.f; wx2 = 0.375f / 32.f; }
        }
        wfl[ox] = 0.25f * (wx0 * ytmp[c0] + wx1 * ytmp[c1] + wx2 * ytmp[c2]);
    }
    __syncthreads();   // wfl ready; barrier also drains global_load_lds

    // ---- phase C: residual cost, shared-frac 6-tap window; c = 2j+h ----
    {
        float disp = wfl[w];
        float xs = (float)w - disp;
        float xbf = floorf(xs);
        float f = xs - xbf;
        int xb = (int)xbf;                 // in [w-23, w]
        const float* sr = &frs1p[0][FR1_GUARD + xb - 2];

        float cost[NK];
#pragma unroll
        for (int k = 0; k < NK; ++k) cost[k] = 0.f;
#pragma unroll
        for (int j = 0; j < 16; ++j) {
            int c = 2 * j + hh;
            const float* row = sr + c * FR1_STRIDE;
            float g0 = row[0], g1 = row[1], g2 = row[2];
            float g3 = row[3], g4 = row[4], g5 = row[5];
            float flvj = flv[j];
            cost[0] += fabsf(flvj - (g0 + f * (g1 - g0)));
            cost[1] += fabsf(flvj - (g1 + f * (g2 - g1)));
            cost[2] += fabsf(flvj - (g2 + f * (g3 - g2)));
            cost[3] += fabsf(flvj - (g3 + f * (g4 - g3)));
            cost[4] += fabsf(flvj - (g5 * f + g4 * (1.f - f)));
        }
#pragma unroll
        for (int k = 0; k < NK; ++k) cost[k] += __shfl_xor(cost[k], 1);
        if (hh == 0) {
            float m = cost[0];
#pragma unroll
            for (int k = 1; k < NK; ++k) m = fminf(m, cost[k]);
            float s = 0.f, sd = 0.f;
#pragma unroll
            for (int k = 0; k < NK; ++k) {
                float e = expf(m - cost[k]);
                s += e;
                sd += (float)(k - 2) * e;
            }
            pl1[(size_t)blk * W1 + w] = 4.f * (sd / s);
        }
    }
}

// ---------------------------------------------------------------------------
// K3: final — separable upsample. One block per output row (b,y); y-lerp
// pl0/pl1 rows into LDS once, then x-lerp from LDS. Pure write-bound.
// ---------------------------------------------------------------------------
__global__ __launch_bounds__(256) void k_final(const float* __restrict__ pl0,
                                               const float* __restrict__ pl1,
                                               float* __restrict__ out) {
    const int blk = blockIdx.x;            // b*IMH + y
    const int b = blk >> 9, y = blk & (IMH - 1);
    const int tid = threadIdx.x;
    __shared__ float a0[W0];
    __shared__ float a1[W1];

    const float* p0b = pl0 + (size_t)b * H0 * W0;
    const float* p1b = pl1 + (size_t)b * H1 * W1;

    float sy0 = (y + 0.5f) * 0.125f - 0.5f;
    float y0f = floorf(sy0);
    float fy0 = sy0 - y0f;
    int r0 = (int)y0f;
    int r0c = min(max(r0, 0), H0 - 1), r1c = min(max(r0 + 1, 0), H0 - 1);

    float sy1 = (y + 0.5f) * 0.25f - 0.5f;
    float y1f = floorf(sy1);
    float fy1 = sy1 - y1f;
    int s0 = (int)y1f;
    int s0c = min(max(s0, 0), H1 - 1), s1c = min(max(s0 + 1, 0), H1 - 1);

    if (tid < W0) {
        float u = p0b[r0c * W0 + tid], v = p0b[r1c * W0 + tid];
        a0[tid] = u + fy0 * (v - u);
    }
    {
        float u = p1b[s0c * W1 + tid], v = p1b[s1c * W1 + tid];
        a1[tid] = u + fy1 * (v - u);
    }
    __syncthreads();

    float v0[4], v1[4];
#pragma unroll
    for (int i = 0; i < 4; ++i) {
        int x = tid * 4 + i;
        float sx0 = (x + 0.5f) * 0.125f - 0.5f;
        float x0f = floorf(sx0);
        float fx0 = sx0 - x0f;
        int c0 = (int)x0f;
        int c0c = min(max(c0, 0), W0 - 1), c1c = min(max(c0 + 1, 0), W0 - 1);
        float p0 = a0[c0c] + fx0 * (a0[c1c] - a0[c0c]);

        float sx1 = (x + 0.5f) * 0.25f - 0.5f;
        float x1f = floorf(sx1);
        float fx1 = sx1 - x1f;
        int d0 = (int)x1f;
        int d0c = min(max(d0, 0), W1 - 1), d1c = min(max(d0 + 1, 0), W1 - 1);
        float p1 = a1[d0c] + fx1 * (a1[d1c] - a1[d0c]);

        v0[i] = p0;
        v1[i] = p1 + p0;
    }
    const size_t NPXQ = (size_t)NB * IMH * IMW / 4;
    size_t t = (size_t)blk * 256 + tid;
    ((float4*)out)[t] = make_float4(v0[0], v0[1], v0[2], v0[3]);
    ((float4*)out)[NPXQ + t] = make_float4(v1[0], v1[1], v1[2], v1[3]);
}

// ---------------------------------------------------------------------------
extern "C" void kernel_launch(void* const* d_in, const int* in_sizes, int n_in,
                              void* d_out, int out_size, void* d_ws, size_t ws_size,
                              hipStream_t stream) {
    const float* fl0 = (const float*)d_in[0];
    const float* fr0 = (const float*)d_in[1];
    const float* fl1 = (const float*)d_in[2];
    const float* fr1 = (const float*)d_in[3];
    float* out = (float*)d_out;

    float* ws = (float*)d_ws;
    float* pl0 = ws;                 // 32768 floats
    float* pl1 = ws + 32768;         // 131072 floats

    k_cost0<<<NB * H0 * 2, 512, 0, stream>>>(fl0, fr0, pl0);
    k_cost1<<<NB * H1, 512, 0, stream>>>(fl1, fr1, pl0, pl1);
    k_final<<<NB * IMH, 256, 0, stream>>>(pl0, pl1, out);
}